// Round 4
// baseline (557.738 us; speedup 1.0000x reference)
//
#include <hip/hip_runtime.h>
#include <cstdint>
#include <cstddef>

// ---------------------------------------------------------------------------
// BsPINN forward, f16 MFMA (round 15).
// R14 post-mortem (layer1 109us, MfmaUtil 26%): 256^2 tile = 1 block/CU; the
// per-tile vmcnt(0) barrier drain exposes full DMA latency (no co-resident
// block to overlap). ~4000 cyc/tile vs ~500 cyc content. Two structure
// experiments lost to baseline => revert to the PROVEN m97 geometry:
//   128x128 tile, 256 threads (4 waves, 2m x 2n, wave 64x64, acc[4][4]),
//   BK=32, SINGLE-buffered 16 KiB LDS, two __syncthreads per K-tile,
//   global_load_lds width-16 staging. Measured (learn_hip m97/m103/m151):
//   874-912 TF at ~3 blocks/CU — inter-block overlap hides the drain stall;
//   gload_lds beats reg-staging 874 vs 646 at this exact tile (m151).
// Kept from this session (both verified on this problem):
//   - zero-conflict XOR swizzle via pre-swizzled global source (slot ^=
//     (row>>1)&3): SQ_LDS_BANK_CONFLICT 8.4M -> 0, absmax unchanged.
//   - fused layer3 epilogue (tanh . W_last -> shfl reduce -> atomicAdd).
// Dropped: setprio (m190: negative on lockstep 2-barrier), hand vmcnt,
// double buffer, 256^2 tile. Occupancy target: ~130-165 VGPR -> 3 waves/SIMD.
// K-loop per tile: sync1 (prior reads retired -> safe overwrite); STAGE(t)
// 4x gload16; sync2 (vmcnt(0) drain = tile landed); 8 ds_read_b128 + 16 MFMA.
// ---------------------------------------------------------------------------

typedef _Float16  f16x8   __attribute__((ext_vector_type(8)));
typedef float     floatx4 __attribute__((ext_vector_type(4)));
typedef float     floatx8 __attribute__((ext_vector_type(8)));

__device__ __forceinline__ float tanh_fast(float x) {
    float e = __expf(2.0f * x);
    return 1.0f - 2.0f / (e + 1.0f);
}

__device__ __forceinline__ void gload16(const _Float16* g, _Float16* l) {
    __builtin_amdgcn_global_load_lds(
        (const __attribute__((address_space(1))) unsigned int*)g,
        (__attribute__((address_space(3))) unsigned int*)l, 16, 0, 0);
}

// ---------------------------------------------------------------------------
// Weight transpose + f16 convert: fp32 W[K=1024][N=1024] -> f16 Wt[N][K].
// ---------------------------------------------------------------------------
__global__ __launch_bounds__(256)
void transposeH(const float* __restrict__ W, _Float16* __restrict__ Wt) {
    __shared__ float tile[32][33];
    const int tx = threadIdx.x & 31;
    const int ty = threadIdx.x >> 5;     // 0..7
    #pragma unroll
    for (int j = 0; j < 4; ++j) {
        int r = ty + j * 8;
        tile[r][tx] = W[(size_t)(blockIdx.y * 32 + r) * 1024 + blockIdx.x * 32 + tx];
    }
    __syncthreads();
    #pragma unroll
    for (int j = 0; j < 4; ++j) {
        int r = ty + j * 8;
        Wt[(size_t)(blockIdx.x * 32 + r) * 1024 + blockIdx.y * 32 + tx] =
            (_Float16)tile[tx][r];
    }
}

// ---------------------------------------------------------------------------
// out[row] := b_last (fp32) — re-initialized every call before layer3 atomics.
// ---------------------------------------------------------------------------
__global__ __launch_bounds__(256)
void init_out(float* __restrict__ out, const float* __restrict__ bl) {
    out[blockIdx.x * 256 + threadIdx.x] = bl[0];
}

// ---------------------------------------------------------------------------
// Layer 0 (fp32 in): h0 = tanh(xa*W0[0][:] + xb*W0[1][:] + b0) -> f16.
// ---------------------------------------------------------------------------
__global__ __launch_bounds__(256)
void layer0_kernel(const float* __restrict__ X, const float* __restrict__ W0,
                   const float* __restrict__ b0, _Float16* __restrict__ H) {
    const int idx = blockIdx.x * 256 + threadIdx.x;
    const int row = idx >> 7;
    const int j0  = (idx & 127) << 3;
    const float x0 = X[row * 2 + 0];
    const float x1 = X[row * 2 + 1];
    const float xa = x0 * 0.31830988618379067f - 1.0f;   // x0/pi - 1
    const float xb = 2.0f * x1 - 1.0f;
    floatx8 wa = *(const floatx8*)(W0 + j0);
    floatx8 wb = *(const floatx8*)(W0 + 1024 + j0);
    floatx8 bb = *(const floatx8*)(b0 + j0);
    f16x8 o;
    #pragma unroll
    for (int j = 0; j < 8; ++j) {
        float v = fmaf(xa, wa[j], fmaf(xb, wb[j], bb[j]));
        o[j] = (_Float16)tanh_fast(v);
    }
    *(f16x8*)(H + (size_t)row * 1024 + j0) = o;
}

// ---------------------------------------------------------------------------
// GEMM + bias + tanh, f16. 128x128 tile, 256 threads = 4 waves (2m x 2n),
// each wave 64x64 via 4x4 16x16x32 frags (64 acc VGPR). BK=32.
// LDS: As[4096], Bs[4096] f16 = 16 KiB, single-buffered (m97 structure).
// K-loop: sync1; STAGE(t) [4 gload16/thread]; sync2 [vmcnt(0) drain = tile
// landed]; 8 ds_read_b128 + 16 MFMA per wave. ~3 blocks/CU hide the drain.
// Swizzle: 16B slot s of a 64B k-row stored at s ^ ((row>>1)&3); global
// source pre-swizzled (involution), LDS dest lane-linear (DMA requirement),
// ds_read applies same XOR => conflict-free (verified 0 in R12/R14).
// KB = diag block: cols [n0,n0+128) need k in [(n0/KB)*KB, +KB).
// FUSE: per-row partial of tanh(pre) . Wl over this wave's 64 cols,
// shfl-reduce over 16 r-lanes, one fp32 atomic per row (out pre-init b_last).
// ---------------------------------------------------------------------------
template <bool FUSE>
__global__ __launch_bounds__(256)
void gemm128(const _Float16* __restrict__ A, const _Float16* __restrict__ Bt,
             const float* __restrict__ bias, _Float16* __restrict__ C,
             const float* __restrict__ Wl, float* __restrict__ out, int KB) {
    __shared__ _Float16 As[4096];   // 8 KB: 128 rows x 32 k
    __shared__ _Float16 Bs[4096];   // 8 KB

    const int tid  = threadIdx.x;
    const int lane = tid & 63;
    const int w    = tid >> 6;                 // 0..3

    const int m0 = blockIdx.x << 7;            // m fast (proven cache order)
    const int n0 = blockIdx.y << 7;

    const int kbeg = (n0 / KB) * KB;
    const int NT   = KB >> 5;                  // K-tiles of 32

    // ---- staging: 512 16B-chunks per tile per matrix; 2 A + 2 B per thread.
    // chunk c -> row c>>2, phys slot c&3; pre-swizzled source slot:
    // sl = (c&3) ^ ((row>>1)&3). LDS dest lane-linear (DMA requirement).
    const int c0  = tid;
    const int c1  = tid + 256;
    const int rw0 = c0 >> 2, sl0 = (c0 & 3) ^ ((rw0 >> 1) & 3);
    const int rw1 = c1 >> 2, sl1 = (c1 & 3) ^ ((rw1 >> 1) & 3);
    const _Float16* gA0 = A  + (size_t)(m0 + rw0) * 1024 + kbeg + sl0 * 8;
    const _Float16* gA1 = A  + (size_t)(m0 + rw1) * 1024 + kbeg + sl1 * 8;
    const _Float16* gB0 = Bt + (size_t)(n0 + rw0) * 1024 + kbeg + sl0 * 8;
    const _Float16* gB1 = Bt + (size_t)(n0 + rw1) * 1024 + kbeg + sl1 * 8;
    const int ldsC0 = c0 * 8, ldsC1 = c1 * 8;  // elem offsets (lane-linear)

    // ---- frag read addressing (same involution on the read side)
    const int r   = lane & 15, q = lane >> 4;
    const int swz = (q ^ ((r >> 1) & 3)) << 3; // elem offset of 16B slot
    const int wm  = (w & 1) << 6;              // 0 / 64
    const int wn  = (w >> 1) << 6;             // 0 / 64

    floatx4 acc[4][4];
    #pragma unroll
    for (int i = 0; i < 4; ++i)
        #pragma unroll
        for (int j = 0; j < 4; ++j)
            acc[i][j] = floatx4{0.f, 0.f, 0.f, 0.f};

#define STAGE(tt) do {                                        \
        const int _ko = (tt) * 32;                            \
        gload16(gA0 + _ko, As + ldsC0);                       \
        gload16(gA1 + _ko, As + ldsC1);                       \
        gload16(gB0 + _ko, Bs + ldsC0);                       \
        gload16(gB1 + _ko, Bs + ldsC1);                       \
    } while (0)

    for (int t = 0; t < NT; ++t) {
        __syncthreads();                       // prior tile's reads retired
        STAGE(t);
        __syncthreads();                       // vmcnt(0) drain: tile t in LDS

        f16x8 af[4], bf[4];
        #pragma unroll
        for (int i = 0; i < 4; ++i) {
            af[i] = *(const f16x8*)(As + (wm + i * 16 + r) * 32 + swz);
            bf[i] = *(const f16x8*)(Bs + (wn + i * 16 + r) * 32 + swz);
        }
        #pragma unroll
        for (int i = 0; i < 4; ++i)
            #pragma unroll
            for (int j = 0; j < 4; ++j)
                acc[i][j] = __builtin_amdgcn_mfma_f32_16x16x32_f16(af[i], bf[j], acc[i][j], 0, 0, 0);
    }
#undef STAGE

    // Epilogue. C/D layout: col=lane&15 (within 16), row=(lane>>4)*4+reg.
    float bv[4], wlv[4];
    #pragma unroll
    for (int j = 0; j < 4; ++j) {
        const int col = n0 + wn + j * 16 + r;
        bv[j] = bias[col];
        if (FUSE) wlv[j] = Wl[col];
    }
    #pragma unroll
    for (int i = 0; i < 4; ++i) {
        const int row0 = m0 + wm + i * 16 + q * 4;
        #pragma unroll
        for (int rr = 0; rr < 4; ++rr) {
            if (!FUSE) {
                #pragma unroll
                for (int j = 0; j < 4; ++j) {
                    float o = tanh_fast(acc[i][j][rr] + bv[j]);
                    const int col = n0 + wn + j * 16 + r;
                    C[(size_t)(row0 + rr) * 1024 + col] = (_Float16)o;
                }
            } else {
                float p = 0.f;
                #pragma unroll
                for (int j = 0; j < 4; ++j)
                    p = fmaf(tanh_fast(acc[i][j][rr] + bv[j]), wlv[j], p);
                p += __shfl_down(p, 8);
                p += __shfl_down(p, 4);
                p += __shfl_down(p, 2);
                p += __shfl_down(p, 1);
                if (r == 0) atomicAdd(out + row0 + rr, p);
            }
        }
    }
}

// ---------------------------------------------------------------------------
extern "C" void kernel_launch(void* const* d_in, const int* in_sizes, int n_in,
                              void* d_out, int out_size, void* d_ws, size_t ws_size,
                              hipStream_t stream) {
    const float* X  = (const float*)d_in[0];
    const float* W0 = (const float*)d_in[1];
    const float* b0 = (const float*)d_in[2];
    const float* W1 = (const float*)d_in[3];
    const float* b1 = (const float*)d_in[4];
    const float* W2 = (const float*)d_in[5];
    const float* b2 = (const float*)d_in[6];
    const float* W3 = (const float*)d_in[7];
    const float* b3 = (const float*)d_in[8];
    const float* Wl = (const float*)d_in[9];
    const float* bl = (const float*)d_in[10];
    float* out = (float*)d_out;

    const int Nrows = in_sizes[0] / 2;                 // 65536
    const size_t WT = 1024 * 1024;                     // elems per f16 weight plane
    const size_t wt_bytes = 3 * WT * 2;                // 6 MiB
    const size_t slack = 512;

    // chunk rows R (pow2, multiple of 256): 2 f16 planes must fit ws.
    int R = 0;
    const int Rcap = Nrows < 32768 ? Nrows : 32768;
    for (int r = Rcap; r >= 256; r >>= 1)
        if ((size_t)2 * r * 2048 + wt_bytes + slack <= ws_size) { R = r; break; }
    if (!R) return;

    _Float16* wsp = (_Float16*)d_ws;
    _Float16* Wt1 = wsp;
    _Float16* Wt2 = Wt1 + WT;
    _Float16* Wt3 = Wt2 + WT;
    const size_t plane = (size_t)R * 1024;
    _Float16* P0 = Wt3 + WT;
    _Float16* P1 = P0 + plane;

    const dim3 tb(256);
    transposeH<<<dim3(32, 32), tb, 0, stream>>>(W1, Wt1);
    transposeH<<<dim3(32, 32), tb, 0, stream>>>(W2, Wt2);
    transposeH<<<dim3(32, 32), tb, 0, stream>>>(W3, Wt3);
    init_out<<<Nrows / 256, tb, 0, stream>>>(out, bl);

    const int nchunks = Nrows / R;
    for (int c = 0; c < nchunks; ++c) {
        const float* Xc = X + (size_t)c * R * 2;
        float* outc = out + (size_t)c * R;

        layer0_kernel<<<R / 2, tb, 0, stream>>>(Xc, W0, b0, P0);

        const dim3 gg(R / 128, 8);                    // m fast (proven cache order)
        gemm128<false><<<gg, tb, 0, stream>>>(P0, Wt1, b1, P1, nullptr, nullptr, 1024);
        gemm128<false><<<gg, tb, 0, stream>>>(P1, Wt2, b2, P0, nullptr, nullptr, 512);
        gemm128<true ><<<gg, tb, 0, stream>>>(P0, Wt3, b3, nullptr, Wl, outc, 256);
    }
}

// Round 5
// 503.605 us; speedup vs baseline: 1.1075x; 1.1075x over previous
//
#include <hip/hip_runtime.h>
#include <cstdint>
#include <cstddef>

// ---------------------------------------------------------------------------
// BsPINN forward, f16 MFMA (round 16).
// R12-R15 post-mortem: three structure rewrites all lost to R11 (490us).
//   - R15 (m97 gload_lds 128^2): sync2's vmcnt(0) drain exposes full staging
//     latency every K-tile (A-panels stream, not L2-hot; ~2.3 blocks/CU can't
//     cover). 118us vs R11's 93us for layer1.
//   - R11's reg-staged prefetch IS the async-STAGE split (T14): t+1 global
//     loads issue after sync2, vmcnt-wait lands at next iter's LDS write ->
//     latency hidden under ds_read+MFMA. Keep it.
// R16 = R11 verbatim + the two session-verified deltas:
//   1. XOR swizzle on LDS write/read (reg-staging allows swizzled ds_write;
//      global loads stay linear/coalesced). Read pattern identical to
//      R14/R15's measured-zero-conflict reads. Kills R11's 8.4M conflict
//      cycles (~15% of critical path).
//   2. Rcap lifted to Nrows: single 65536-row chunk if workspace fits
//      (262MB planes) -> half the launches; auto-fallback to 32768.
// Structure (unchanged from R11): 256x128 tile, 512 threads = 8 waves
// (4m x 2n), wave 64x64, acc[4][4], BK=32, 24KB LDS single-buffered,
// two __syncthreads per K-tile, reg prefetch of t+1. m-fast grid.
// Epilogues unchanged (absmax 2.44e-4 validated): bias+tanh store, or fused
// tanh . W_last dot -> shfl-reduce -> atomicAdd(out) with out pre-init b_last.
// ---------------------------------------------------------------------------

typedef _Float16  f16x8   __attribute__((ext_vector_type(8)));
typedef float     floatx4 __attribute__((ext_vector_type(4)));
typedef float     floatx8 __attribute__((ext_vector_type(8)));

__device__ __forceinline__ float tanh_fast(float x) {
    float e = __expf(2.0f * x);
    return 1.0f - 2.0f / (e + 1.0f);
}

// ---------------------------------------------------------------------------
// Weight transpose + f16 convert: fp32 W[K=1024][N=1024] -> f16 Wt[N][K].
// ---------------------------------------------------------------------------
__global__ __launch_bounds__(256)
void transposeH(const float* __restrict__ W, _Float16* __restrict__ Wt) {
    __shared__ float tile[32][33];
    const int tx = threadIdx.x & 31;
    const int ty = threadIdx.x >> 5;     // 0..7
    #pragma unroll
    for (int j = 0; j < 4; ++j) {
        int r = ty + j * 8;
        tile[r][tx] = W[(size_t)(blockIdx.y * 32 + r) * 1024 + blockIdx.x * 32 + tx];
    }
    __syncthreads();
    #pragma unroll
    for (int j = 0; j < 4; ++j) {
        int r = ty + j * 8;
        Wt[(size_t)(blockIdx.x * 32 + r) * 1024 + blockIdx.y * 32 + tx] =
            (_Float16)tile[tx][r];
    }
}

// ---------------------------------------------------------------------------
// out[row] := b_last (fp32) — re-initialized every call before layer3 atomics.
// ---------------------------------------------------------------------------
__global__ __launch_bounds__(256)
void init_out(float* __restrict__ out, const float* __restrict__ bl) {
    out[blockIdx.x * 256 + threadIdx.x] = bl[0];
}

// ---------------------------------------------------------------------------
// Layer 0 (fp32 in): h0 = tanh(xa*W0[0][:] + xb*W0[1][:] + b0) -> f16.
// ---------------------------------------------------------------------------
__global__ __launch_bounds__(256)
void layer0_kernel(const float* __restrict__ X, const float* __restrict__ W0,
                   const float* __restrict__ b0, _Float16* __restrict__ H) {
    const int idx = blockIdx.x * 256 + threadIdx.x;
    const int row = idx >> 7;
    const int j0  = (idx & 127) << 3;
    const float x0 = X[row * 2 + 0];
    const float x1 = X[row * 2 + 1];
    const float xa = x0 * 0.31830988618379067f - 1.0f;   // x0/pi - 1
    const float xb = 2.0f * x1 - 1.0f;
    floatx8 wa = *(const floatx8*)(W0 + j0);
    floatx8 wb = *(const floatx8*)(W0 + 1024 + j0);
    floatx8 bb = *(const floatx8*)(b0 + j0);
    f16x8 o;
    #pragma unroll
    for (int j = 0; j < 8; ++j) {
        float v = fmaf(xa, wa[j], fmaf(xb, wb[j], bb[j]));
        o[j] = (_Float16)tanh_fast(v);
    }
    *(f16x8*)(H + (size_t)row * 1024 + j0) = o;
}

// ---------------------------------------------------------------------------
// GEMM + bias + tanh, f16. 256x128 tile, 512 threads = 8 waves (4m x 2n),
// each wave 64x64 via 4x4 16x16x32 frags. BK=32, two-barrier K-loop with
// register prefetch of tile t+1 (T14 async split: the vmcnt wait for t+1
// lands at the NEXT iter's LDS write -> global latency hidden under
// ds_read+MFMA). KB = diag block: cols [n0,n0+128) need k in
// [(n0/KB)*KB, +KB).
// Swizzle (new vs R11): 16B slot s of each 64B k-row stored at
// s ^ ((row>>1)&3). Write side: ds_write address swizzled (global load
// stays linear). Read side: same involution (measured 0 conflicts in
// R14/R15; R11's unswizzled reads cost 8.4M conflict cycles).
// FUSE: per-row partial of tanh(pre) . Wl over this wave's 64 cols,
// shfl-reduce over 16 r-lanes, one fp32 atomic per row (out pre-init b_last).
// ---------------------------------------------------------------------------
template <bool FUSE>
__global__ __launch_bounds__(512)
void gemm_tanh_f16(const _Float16* __restrict__ A, const _Float16* __restrict__ Bt,
                   const float* __restrict__ bias, _Float16* __restrict__ C,
                   const float* __restrict__ Wl, float* __restrict__ out, int KB) {
    __shared__ _Float16 As[256 * 32];   // 16 KB
    __shared__ _Float16 Bs[128 * 32];   // 8 KB

    const int tid  = threadIdx.x;
    const int lane = tid & 63;
    const int wave = tid >> 6;
    const int m0 = blockIdx.x * 256;          // m fast (proven cache order)
    const int n0 = blockIdx.y * 128;
    const int kbeg   = (n0 / KB) * KB;
    const int kiters = KB >> 5;
    const int wm = (wave & 3) << 6;           // 0,64,128,192
    const int wn = (wave >> 2) << 6;          // 0,64
    const int r = lane & 15;
    const int q = lane >> 4;

    // Staging: A = 1024 16B slots (2/thread), B = 512 slots (1/thread).
    const int rowA0 = tid >> 2;               // 0..127
    const int rowA1 = 128 + rowA0;            // 128..255
    const int seg   = (tid & 3) << 3;         // 8-elem segment of 32-k row
    const size_t gA0 = (size_t)(m0 + rowA0) * 1024 + kbeg + seg;
    const size_t gA1 = (size_t)(m0 + rowA1) * 1024 + kbeg + seg;
    const size_t gB  = (size_t)(n0 + rowA0) * 1024 + kbeg + seg;  // rowB==rowA0
    // LDS write offsets: slot swizzled by row (involution; rowA1 = rowA0+128
    // keeps the same XOR, but compute per-row for clarity).
    const int slA0 = ((tid & 3) ^ ((rowA0 >> 1) & 3)) << 3;
    const int slA1 = ((tid & 3) ^ ((rowA1 >> 1) & 3)) << 3;
    const int ldsA0 = (rowA0 << 5) + slA0;
    const int ldsA1 = (rowA1 << 5) + slA1;
    const int ldsB  = (rowA0 << 5) + slA0;

    floatx4 acc[4][4];
    #pragma unroll
    for (int i = 0; i < 4; ++i)
        #pragma unroll
        for (int j = 0; j < 4; ++j)
            acc[i][j] = floatx4{0.f, 0.f, 0.f, 0.f};

    // Prologue: k-tile 0 into regs.
    f16x8 va0 = *(const f16x8*)(A + gA0);
    f16x8 va1 = *(const f16x8*)(A + gA1);
    f16x8 vb  = *(const f16x8*)(Bt + gB);

    // Frag read: same involution on the read side (measured conflict-free).
    const int swz = (q ^ ((r >> 1) & 3)) << 3;

    for (int t = 0; t < kiters; ++t) {
        __syncthreads();                      // prior iter's ds_reads done
        *(f16x8*)(As + ldsA0) = va0;
        *(f16x8*)(As + ldsA1) = va1;
        *(f16x8*)(Bs + ldsB)  = vb;
        __syncthreads();                      // tile t visible

        if (t + 1 < kiters) {                 // prefetch t+1 (overlaps MFMA)
            const size_t d = (size_t)(t + 1) << 5;
            va0 = *(const f16x8*)(A + gA0 + d);
            va1 = *(const f16x8*)(A + gA1 + d);
            vb  = *(const f16x8*)(Bt + gB + d);
        }

        f16x8 af[4], bf[4];
        #pragma unroll
        for (int i = 0; i < 4; ++i) {
            af[i] = *(const f16x8*)(As + (wm + i * 16 + r) * 32 + swz);
            bf[i] = *(const f16x8*)(Bs + (wn + i * 16 + r) * 32 + swz);
        }
        #pragma unroll
        for (int i = 0; i < 4; ++i)
            #pragma unroll
            for (int j = 0; j < 4; ++j)
                acc[i][j] = __builtin_amdgcn_mfma_f32_16x16x32_f16(af[i], bf[j], acc[i][j], 0, 0, 0);
    }

    // Epilogue. C/D layout: col=lane&15 (within 16), row=(lane>>4)*4+reg.
    float bv[4], wlv[4];
    #pragma unroll
    for (int j = 0; j < 4; ++j) {
        const int col = n0 + wn + j * 16 + r;
        bv[j] = bias[col];
        if (FUSE) wlv[j] = Wl[col];
    }
    #pragma unroll
    for (int i = 0; i < 4; ++i) {
        const int row0 = m0 + wm + i * 16 + q * 4;
        #pragma unroll
        for (int rr = 0; rr < 4; ++rr) {
            if (!FUSE) {
                #pragma unroll
                for (int j = 0; j < 4; ++j) {
                    float o = tanh_fast(acc[i][j][rr] + bv[j]);
                    const int col = n0 + wn + j * 16 + r;
                    C[(size_t)(row0 + rr) * 1024 + col] = (_Float16)o;
                }
            } else {
                float p = 0.f;
                #pragma unroll
                for (int j = 0; j < 4; ++j)
                    p = fmaf(tanh_fast(acc[i][j][rr] + bv[j]), wlv[j], p);
                // reduce across the 16 r-lanes (lane = q*16 + r)
                p += __shfl_down(p, 8);
                p += __shfl_down(p, 4);
                p += __shfl_down(p, 2);
                p += __shfl_down(p, 1);
                if (r == 0) atomicAdd(out + row0 + rr, p);
            }
        }
    }
}

// ---------------------------------------------------------------------------
extern "C" void kernel_launch(void* const* d_in, const int* in_sizes, int n_in,
                              void* d_out, int out_size, void* d_ws, size_t ws_size,
                              hipStream_t stream) {
    const float* X  = (const float*)d_in[0];
    const float* W0 = (const float*)d_in[1];
    const float* b0 = (const float*)d_in[2];
    const float* W1 = (const float*)d_in[3];
    const float* b1 = (const float*)d_in[4];
    const float* W2 = (const float*)d_in[5];
    const float* b2 = (const float*)d_in[6];
    const float* W3 = (const float*)d_in[7];
    const float* b3 = (const float*)d_in[8];
    const float* Wl = (const float*)d_in[9];
    const float* bl = (const float*)d_in[10];
    float* out = (float*)d_out;

    const int Nrows = in_sizes[0] / 2;                 // 65536
    const size_t WT = 1024 * 1024;                     // elems per f16 weight plane
    const size_t wt_bytes = 3 * WT * 2;                // 6 MiB
    const size_t slack = 512;

    // chunk rows R (pow2, multiple of 256): 2 f16 planes must fit ws.
    // Rcap lifted to Nrows (was 32768): single-chunk if workspace allows.
    int R = 0;
    const int Rcap = Nrows;
    for (int r = Rcap; r >= 256; r >>= 1)
        if ((size_t)2 * r * 2048 + wt_bytes + slack <= ws_size) { R = r; break; }
    if (!R) return;

    _Float16* wsp = (_Float16*)d_ws;
    _Float16* Wt1 = wsp;
    _Float16* Wt2 = Wt1 + WT;
    _Float16* Wt3 = Wt2 + WT;
    const size_t plane = (size_t)R * 1024;
    _Float16* P0 = Wt3 + WT;
    _Float16* P1 = P0 + plane;

    const dim3 tb(256);
    transposeH<<<dim3(32, 32), tb, 0, stream>>>(W1, Wt1);
    transposeH<<<dim3(32, 32), tb, 0, stream>>>(W2, Wt2);
    transposeH<<<dim3(32, 32), tb, 0, stream>>>(W3, Wt3);
    init_out<<<Nrows / 256, tb, 0, stream>>>(out, bl);

    const int nchunks = Nrows / R;
    for (int c = 0; c < nchunks; ++c) {
        const float* Xc = X + (size_t)c * R * 2;
        float* outc = out + (size_t)c * R;

        layer0_kernel<<<R / 2, tb, 0, stream>>>(Xc, W0, b0, P0);

        const dim3 tg(512);
        const dim3 gg(R / 256, 8);                    // m fast
        gemm_tanh_f16<false><<<gg, tg, 0, stream>>>(P0, Wt1, b1, P1, nullptr, nullptr, 1024);
        gemm_tanh_f16<false><<<gg, tg, 0, stream>>>(P1, Wt2, b2, P0, nullptr, nullptr, 512);
        gemm_tanh_f16<true ><<<gg, tg, 0, stream>>>(P0, Wt3, b3, nullptr, Wl, outc, 256);
    }
}